// Round 1
// baseline (163.298 us; speedup 1.0000x reference)
//
#include <hip/hip_runtime.h>
#include <hip/hip_bf16.h>
#include <stdint.h>

#define NEGV (-1e30f)

constexpr int Bc = 128;
constexpr int Tc = 160;
constexpr int Cc = 6625;
constexpr int Lc = 25;
constexpr int Sc = 51;   // 2*L + 1

// Kernel 1: per (b,t) row — online logsumexp over C classes, then gather the
// S=51 extended-label log-probs (masked to NEG beyond 2*len+1).
__global__ __launch_bounds__(256) void k_lse_gather(
    const float* __restrict__ pred, const int* __restrict__ targets,
    const int* __restrict__ tlen, float* __restrict__ lp_ext)
{
    const int row = blockIdx.x;           // b*T + t
    const int b   = row / Tc;
    const int tid = threadIdx.x;
    const float* p = pred + (size_t)row * Cc;

    // online (max, sum) over this thread's strided slice, float4 main body
    float m = -3.0e38f, s = 0.0f;

    const uintptr_t addr = (uintptr_t)p;
    int head = (int)(((16u - (addr & 15u)) & 15u) >> 2);   // floats to 16B align
    if (head > Cc) head = Cc;
    if (tid < head) { m = p[tid]; s = 1.0f; }

    const int n4 = (Cc - head) >> 2;
    const float4* p4 = (const float4*)(p + head);
    for (int i = tid; i < n4; i += 256) {
        float4 v = p4[i];
        float m4 = fmaxf(fmaxf(v.x, v.y), fmaxf(v.z, v.w));
        float mn = fmaxf(m, m4);
        s = s * __expf(m - mn)
          + __expf(v.x - mn) + __expf(v.y - mn)
          + __expf(v.z - mn) + __expf(v.w - mn);
        m = mn;
    }
    const int tailStart = head + 4 * n4;
    const int tailN = Cc - tailStart;
    if (tid < tailN) {
        float v = p[tailStart + tid];
        float mn = fmaxf(m, v);
        s = s * __expf(m - mn) + __expf(v - mn);
        m = mn;
    }

    // wave (64-lane) reduction of (m, s)
    #pragma unroll
    for (int off = 1; off < 64; off <<= 1) {
        float mo = __shfl_xor(m, off);
        float so = __shfl_xor(s, off);
        float mn = fmaxf(m, mo);
        s = s * __expf(m - mn) + so * __expf(mo - mn);
        m = mn;
    }

    __shared__ float sm[4], ss[4];
    __shared__ float sD;
    const int wave = tid >> 6, lane = tid & 63;
    if (lane == 0) { sm[wave] = m; ss[wave] = s; }
    __syncthreads();
    if (tid == 0) {
        float M = sm[0], S = ss[0];
        #pragma unroll
        for (int w = 1; w < 4; ++w) {
            float mn = fmaxf(M, sm[w]);
            S = S * __expf(M - mn) + ss[w] * __expf(sm[w] - mn);
            M = mn;
        }
        sD = M + __logf(S);      // log-softmax denominator
    }
    __syncthreads();
    const float D = sD;

    if (tid < Sc) {
        const int len = tlen[b];
        const int cls = (tid & 1) ? targets[b * Lc + (tid >> 1)] : 0;
        const bool valid = tid < (2 * len + 1);
        lp_ext[(size_t)row * Sc + tid] = valid ? (p[cls] - D) : NEGV;
    }
}

// Kernel 2: one wave per batch item; lane s owns CTC state s. Sequential
// alpha recursion over T with shfl_up neighbor access and lse3.
__global__ __launch_bounds__(64) void k_alpha(
    const float* __restrict__ lp_ext, const int* __restrict__ targets,
    const int* __restrict__ tlen, float* __restrict__ loss_b)
{
    const int b = blockIdx.x;
    const int s = threadIdx.x;
    const int len = tlen[b];

    bool skip = false;
    if ((s & 1) && s >= 3) {
        int cur  = targets[b * Lc + (s >> 1)];
        int prev = targets[b * Lc + (s >> 1) - 1];
        skip = (cur != prev);
    }

    const float* lp = lp_ext + (size_t)b * Tc * Sc;
    const bool inS = (s < Sc);

    float lp0 = inS ? lp[s] : NEGV;
    float alpha = (s <= 1) ? lp0 : NEGV;
    float lpn = inS ? lp[Sc + s] : NEGV;      // prefetch t=1

    for (int t = 1; t < Tc; ++t) {
        float cur = lpn;
        if (t + 1 < Tc && inS) lpn = lp[(size_t)(t + 1) * Sc + s];  // prefetch

        float a1 = alpha;
        float a2 = __shfl_up(alpha, 1);
        float a3 = __shfl_up(alpha, 2);
        if (s < 1) a2 = NEGV;
        if (s < 2 || !skip) a3 = NEGV;

        float m = fmaxf(fmaxf(a1, a2), a3);
        m = fmaxf(m, NEGV);
        float l = m + __logf(__expf(a1 - m) + __expf(a2 - m) + __expf(a3 - m));
        alpha = cur + l;
    }

    // terminal states: 2*len (final blank), 2*len-1 (final label)
    float ae0 = __shfl(alpha, 2 * len);
    float ae1 = __shfl(alpha, 2 * len - 1);
    if (s == 0) {
        float m = fmaxf(ae0, ae1);
        float lse = m + __logf(__expf(ae0 - m) + __expf(ae1 - m));
        float loss = -lse;
        if (loss >= 1e29f) loss = 0.0f;                 // zero_infinity
        loss_b[b] = loss / fmaxf((float)len, 1.0f);
    }
}

// Kernel 3: mean over B=128.
__global__ __launch_bounds__(128) void k_reduce(
    const float* __restrict__ loss_b, float* __restrict__ out)
{
    const int tid = threadIdx.x;
    float v = loss_b[tid];
    #pragma unroll
    for (int off = 1; off < 64; off <<= 1) v += __shfl_xor(v, off);
    __shared__ float partial[2];
    if ((tid & 63) == 0) partial[tid >> 6] = v;
    __syncthreads();
    if (tid == 0) out[0] = (partial[0] + partial[1]) * (1.0f / (float)Bc);
}

extern "C" void kernel_launch(void* const* d_in, const int* in_sizes, int n_in,
                              void* d_out, int out_size, void* d_ws, size_t ws_size,
                              hipStream_t stream) {
    const float* pred    = (const float*)d_in[0];
    const int*   targets = (const int*)d_in[1];
    const int*   tlen    = (const int*)d_in[2];
    float* out = (float*)d_out;

    float* lp_ext = (float*)d_ws;                           // B*T*S floats
    float* loss_b = lp_ext + (size_t)Bc * Tc * Sc;          // B floats

    hipLaunchKernelGGL(k_lse_gather, dim3(Bc * Tc), dim3(256), 0, stream,
                       pred, targets, tlen, lp_ext);
    hipLaunchKernelGGL(k_alpha, dim3(Bc), dim3(64), 0, stream,
                       lp_ext, targets, tlen, loss_b);
    hipLaunchKernelGGL(k_reduce, dim3(1), dim3(128), 0, stream,
                       loss_b, out);
}

// Round 2
// 161.359 us; speedup vs baseline: 1.0120x; 1.0120x over previous
//
#include <hip/hip_runtime.h>
#include <hip/hip_bf16.h>
#include <stdint.h>

#define NEGV (-1e30f)
#define FILLV (-1e30f)   // exp(FILLV - M) == 0 for any finite M from real data

constexpr int Bc = 128;
constexpr int Tc = 160;
constexpr int Cc = 6625;
constexpr int Lc = 25;
constexpr int Sc = 51;   // 2*L + 1

// Kernel 1: per (b,t) row — two-pass (max, then exp-sum) logsumexp over C
// classes held entirely in registers, then gather the S=51 extended-label
// log-probs (masked to NEG beyond 2*len+1).
__global__ __launch_bounds__(256) void k_lse_gather(
    const float* __restrict__ pred, const int* __restrict__ targets,
    const int* __restrict__ tlen, float* __restrict__ lp_ext)
{
    const int row = blockIdx.x;           // b*T + t
    const int b   = row / Tc;
    const int tid = threadIdx.x;
    const float* p = pred + (size_t)row * Cc;

    const uintptr_t addr = (uintptr_t)p;
    const int head = (int)(((16u - (addr & 15u)) & 15u) >> 2);  // floats to 16B align
    const int n4 = (Cc - head) >> 2;                            // 1655 or 1656
    const float4* p4 = (const float4*)(p + head);
    const int tailStart = head + 4 * n4;
    const int tailN = Cc - tailStart;                           // 0..3

    // ---- issue ALL loads up front (7 float4 + up to 2 scalars per thread) ----
    float4 v[7];
    #pragma unroll
    for (int j = 0; j < 7; ++j) {
        const int i = tid + j * 256;
        if (i < n4) v[j] = p4[i];
        else        v[j] = make_float4(FILLV, FILLV, FILLV, FILLV);
    }
    const float hv = (tid < head)  ? p[tid]             : FILLV;
    const float tv = (tid < tailN) ? p[tailStart + tid] : FILLV;

    // ---- pass 1: max (pure fmax tree, full ILP) ----
    float m = fmaxf(hv, tv);
    #pragma unroll
    for (int j = 0; j < 7; ++j)
        m = fmaxf(m, fmaxf(fmaxf(v[j].x, v[j].y), fmaxf(v[j].z, v[j].w)));

    #pragma unroll
    for (int off = 1; off < 64; off <<= 1)
        m = fmaxf(m, __shfl_xor(m, off));

    __shared__ float red[4];
    __shared__ float sM, sD;
    const int wave = tid >> 6, lane = tid & 63;
    if (lane == 0) red[wave] = m;
    __syncthreads();
    if (tid == 0)
        sM = fmaxf(fmaxf(red[0], red[1]), fmaxf(red[2], red[3]));
    __syncthreads();
    const float M = sM;

    // ---- pass 2: sum of exp(v - M), 4 independent accumulators ----
    float s0 = __expf(hv - M), s1 = __expf(tv - M), s2 = 0.0f, s3 = 0.0f;
    #pragma unroll
    for (int j = 0; j < 7; ++j) {
        s0 += __expf(v[j].x - M);
        s1 += __expf(v[j].y - M);
        s2 += __expf(v[j].z - M);
        s3 += __expf(v[j].w - M);
    }
    float s = (s0 + s1) + (s2 + s3);
    #pragma unroll
    for (int off = 1; off < 64; off <<= 1)
        s += __shfl_xor(s, off);
    if (lane == 0) red[wave] = s;
    __syncthreads();
    if (tid == 0)
        sD = M + __logf(((red[0] + red[1]) + (red[2] + red[3])));
    __syncthreads();
    const float D = sD;

    // ---- gather extended-label log-probs ----
    if (tid < Sc) {
        const int len = tlen[b];
        const int cls = (tid & 1) ? targets[b * Lc + (tid >> 1)] : 0;
        const bool valid = tid < (2 * len + 1);
        lp_ext[(size_t)row * Sc + tid] = valid ? (p[cls] - D) : NEGV;
    }
}

// Kernel 2: one wave per batch item; lane s owns CTC state s. Sequential
// alpha recursion over T with shfl_up neighbor access and lse3.
__global__ __launch_bounds__(64) void k_alpha(
    const float* __restrict__ lp_ext, const int* __restrict__ targets,
    const int* __restrict__ tlen, float* __restrict__ loss_b)
{
    const int b = blockIdx.x;
    const int s = threadIdx.x;
    const int len = tlen[b];

    bool skip = false;
    if ((s & 1) && s >= 3) {
        int cur  = targets[b * Lc + (s >> 1)];
        int prev = targets[b * Lc + (s >> 1) - 1];
        skip = (cur != prev);
    }

    const float* lp = lp_ext + (size_t)b * Tc * Sc;
    const bool inS = (s < Sc);

    float lp0 = inS ? lp[s] : NEGV;
    float alpha = (s <= 1) ? lp0 : NEGV;
    float lpn = inS ? lp[Sc + s] : NEGV;      // prefetch t=1

    for (int t = 1; t < Tc; ++t) {
        float cur = lpn;
        if (t + 1 < Tc && inS) lpn = lp[(size_t)(t + 1) * Sc + s];  // prefetch

        float a1 = alpha;
        float a2 = __shfl_up(alpha, 1);
        float a3 = __shfl_up(alpha, 2);
        if (s < 1) a2 = NEGV;
        if (s < 2 || !skip) a3 = NEGV;

        float m = fmaxf(fmaxf(a1, a2), a3);
        m = fmaxf(m, NEGV);
        float l = m + __logf(__expf(a1 - m) + __expf(a2 - m) + __expf(a3 - m));
        alpha = cur + l;
    }

    // terminal states: 2*len (final blank), 2*len-1 (final label)
    float ae0 = __shfl(alpha, 2 * len);
    float ae1 = __shfl(alpha, 2 * len - 1);
    if (s == 0) {
        float m = fmaxf(ae0, ae1);
        float lse = m + __logf(__expf(ae0 - m) + __expf(ae1 - m));
        float loss = -lse;
        if (loss >= 1e29f) loss = 0.0f;                 // zero_infinity
        loss_b[b] = loss / fmaxf((float)len, 1.0f);
    }
}

// Kernel 3: mean over B=128.
__global__ __launch_bounds__(128) void k_reduce(
    const float* __restrict__ loss_b, float* __restrict__ out)
{
    const int tid = threadIdx.x;
    float v = loss_b[tid];
    #pragma unroll
    for (int off = 1; off < 64; off <<= 1) v += __shfl_xor(v, off);
    __shared__ float partial[2];
    if ((tid & 63) == 0) partial[tid >> 6] = v;
    __syncthreads();
    if (tid == 0) out[0] = (partial[0] + partial[1]) * (1.0f / (float)Bc);
}

extern "C" void kernel_launch(void* const* d_in, const int* in_sizes, int n_in,
                              void* d_out, int out_size, void* d_ws, size_t ws_size,
                              hipStream_t stream) {
    const float* pred    = (const float*)d_in[0];
    const int*   targets = (const int*)d_in[1];
    const int*   tlen    = (const int*)d_in[2];
    float* out = (float*)d_out;

    float* lp_ext = (float*)d_ws;                           // B*T*S floats
    float* loss_b = lp_ext + (size_t)Bc * Tc * Sc;          // B floats

    hipLaunchKernelGGL(k_lse_gather, dim3(Bc * Tc), dim3(256), 0, stream,
                       pred, targets, tlen, lp_ext);
    hipLaunchKernelGGL(k_alpha, dim3(Bc), dim3(64), 0, stream,
                       lp_ext, targets, tlen, loss_b);
    hipLaunchKernelGGL(k_reduce, dim3(1), dim3(128), 0, stream,
                       loss_b, out);
}